// Round 4
// baseline (227.987 us; speedup 1.0000x reference)
//
#include <hip/hip_runtime.h>

#define B_ 16
#define N_ 1024
#define C_ 768
#define E_ 8
#define H_ 192

typedef __bf16 bf16x8 __attribute__((ext_vector_type(8)));
typedef float  f32x4  __attribute__((ext_vector_type(4)));

// ---------------------------------------------------------------------------
// Kernel 1: prep. (a) pack fc1_w/fc2_w to bf16 in MFMA-B-fragment order:
//   pw1[e][kb=c/32][n=h][c%32], pw2[e][kb=h/32][n=c][h%32]
// (b) transpose gate_w to gwT[d][j][c] (f32); rows 0..7 clean, 8..15 noise.
// ---------------------------------------------------------------------------
__global__ __launch_bounds__(256) void prep_kernel(
    const float* __restrict__ w1, const float* __restrict__ w2,
    const float* __restrict__ gw,
    __bf16* __restrict__ pw1, __bf16* __restrict__ pw2,
    float* __restrict__ gwT) {
  int idx = blockIdx.x * 256 + threadIdx.x;            // float4 index
  const int nW4 = (E_ * H_ * C_) / 4;                  // 294912
  if (idx >= nW4) return;
  int flat = idx * 4;
  int e = flat / (H_ * C_);
  int r = flat - e * (H_ * C_);

  // w1: [e][h][c] -> pw1
  {
    float4 a = *(const float4*)(w1 + (size_t)flat);
    int n = r / C_;           // h
    int c = r - n * C_;       // c, %4==0
    size_t o = ((size_t)(e * 24 + (c >> 5)) * 192 + n) * 32 + (c & 31);
    pw1[o + 0] = (__bf16)a.x; pw1[o + 1] = (__bf16)a.y;
    pw1[o + 2] = (__bf16)a.z; pw1[o + 3] = (__bf16)a.w;
  }
  // w2: [e][c][h] -> pw2
  {
    float4 a = *(const float4*)(w2 + (size_t)flat);
    int n = r / H_;           // c index 0..767
    int h = r - n * H_;       // 0..191, %4==0
    size_t o = ((size_t)(e * 6 + (h >> 5)) * 768 + n) * 32 + (h & 31);
    pw2[o + 0] = (__bf16)a.x; pw2[o + 1] = (__bf16)a.y;
    pw2[o + 2] = (__bf16)a.z; pw2[o + 3] = (__bf16)a.w;
  }
  // gwT: [d][c][16] -> [d][j][c]
  if (idx < (4 * 16 * C_) / 4) {
    int f = idx * 4;
    int d = f / (16 * C_);
    int rr = f - d * (16 * C_);
    int j = rr / C_;
    int c = rr - j * C_;      // %4==0
    const float* src = gw + (size_t)d * C_ * 16 + j;
    float4 v;
    v.x = src[(size_t)(c + 0) * 16]; v.y = src[(size_t)(c + 1) * 16];
    v.z = src[(size_t)(c + 2) * 16]; v.w = src[(size_t)(c + 3) * 16];
    *(float4*)(gwT + (size_t)f) = v;
  }
}

// ---------------------------------------------------------------------------
// Kernel 2: gating. Grid = B*64 blocks, 16 tokens each, 256 thr (broadcast
// mapping: 16 lanes share one gwT row -> 4 addrs/wave). Per-block partial
// expert sums -> psums[bid][8] (no atomics, no memset).
// ---------------------------------------------------------------------------
__global__ __launch_bounds__(256, 3) void gate_kernel(
    const float* __restrict__ x, const int* __restrict__ task_ids,
    const float* __restrict__ eps, const float* __restrict__ gwT,
    float* __restrict__ psums) {
  const int b = blockIdx.x >> 6;
  const int token0 = (blockIdx.x & 63) * 16;
  const int tid = threadIdx.x;

  __shared__ __align__(16) float xt[16][772];   // pad 4: 2-way (free) reads
  __shared__ float sc[16][16];
  __shared__ float red[16][8];

  // stage 16x768 f32, coalesced: 3072 float4 / 256 thr = 12 each
  const float* xbase = x + ((size_t)b * N_ + token0) * C_;
  for (int it = 0; it < 12; ++it) {
    int chunk = it * 256 + tid;                 // 0..3071
    int row = chunk / 192;
    int col4 = chunk - row * 192;
    float4 v = *(const float4*)(xbase + (size_t)row * C_ + col4 * 4);
    *(float4*)&xt[row][col4 * 4] = v;
  }
  __syncthreads();

  const int t = tid & 15;
  const int j = tid >> 4;                       // 16 lanes share one j
  const int task = task_ids[b];
  const float* wrow = gwT + ((size_t)task * 16 + j) * C_;
  float acc = 0.0f;
#pragma unroll 4
  for (int c = 0; c < C_; c += 4) {
    float4 xv = *(const float4*)&xt[t][c];
    float4 wv = *(const float4*)(wrow + c);
    acc += xv.x * wv.x + xv.y * wv.y + xv.z * wv.z + xv.w * wv.w;
  }
  sc[t][j] = acc;
  __syncthreads();
  if (j < 8) {
    float clean = sc[t][j];
    float raw = sc[t][j + 8];
    float sp = (raw > 20.0f) ? raw : log1pf(expf(raw));
    red[t][j] = clean +
        eps[((size_t)b * N_ + token0 + t) * E_ + j] * (sp + 0.01f);
  }
  __syncthreads();
  if (tid < 8) {
    float s = 0.0f;
#pragma unroll
    for (int tt = 0; tt < 16; ++tt) s += red[tt][tid];
    psums[(size_t)blockIdx.x * 8 + tid] = s;
  }
}

// ---------------------------------------------------------------------------
// Kernel 3: top-2 + 2-expert adapter. Grid = 256 blocks x 1024 thr
// (16 waves = 4 token-quarters x 4 N-slices -> 4 waves/SIMD, 2x the TLP of
// the 512-thr version), 64 tokens/block, XCD-pinned (bid%8 = XCD, 2
// samples/XCD -> expert weights L2-resident). M per wave = 16 rows.
// GEMM1 prefetch depth 3 ([3][3] rotation), GEMM2 B/A ping-pong depth 2;
// with 4 waves/SIMD, TLP covers what register-depth ILP covered before.
// __launch_bounds__(1024,4) caps VGPR at 128 so the 16-wave block fits.
// MFMA 16x16x32 bf16; C/D: col=lane&15, row=(lane>>4)*4+reg.
// ---------------------------------------------------------------------------
#define SMEM_EXPERT (64 * 776 * 2 + 64 * 200 * 2 + 32)   // 124960 B

__global__ __launch_bounds__(1024, 4) void expert_kernel(
    const float* __restrict__ x, const __bf16* __restrict__ pw1,
    const __bf16* __restrict__ pw2, const float* __restrict__ fc1_b,
    const float* __restrict__ fc2_b, const float* __restrict__ psums,
    float* __restrict__ out) {
  const int bid = blockIdx.x;
  const int sxc = bid >> 3;                    // 0..31 within an XCD
  const int b = (bid & 7) * 2 + (sxc >> 4);    // 2 consecutive samples / XCD
  const int token0 = (sxc & 15) * 64;
  const int tid = threadIdx.x;
  const int wave = tid >> 6;
  const int wm = wave >> 2;                    // token quarter (0..3)
  const int wn = wave & 3;                     // N slice (0..3)
  const int lane = tid & 63;
  const int ln = lane & 15;
  const int q8 = (lane >> 4) * 8;
  const int q4 = (lane >> 4) * 4;
  const int arow = wm * 16;

  extern __shared__ char smem[];
  __bf16 (*xs)[776] = reinterpret_cast<__bf16(*)[776]>(smem);          // 99328
  __bf16 (*hs)[200] = reinterpret_cast<__bf16(*)[200]>(smem + 99328);  // 25600
  float* smc = reinterpret_cast<float*>(smem + 99328 + 25600);         // 32

  // ---- per-sample gate sums: waves 0..7 reduce 64 tile-partials each ------
  if (wave < 8) {
    float v = psums[(((size_t)b << 6) | lane) * 8 + wave];
#pragma unroll
    for (int off = 32; off; off >>= 1) v += __shfl_down(v, off);
    if (lane == 0) smc[wave] = v;
  }
  __syncthreads();

  // top-2 (tie rule matches lax.top_k: strict >, stable)
  int e_idx[2]; float gate_v[2];
  {
    float best = -INFINITY, best2 = -INFINITY;
    int i1 = 0, i2 = 0;
#pragma unroll
    for (int e = 0; e < E_; ++e) {
      float v = smc[e];
      if (v > best) { best2 = best; i2 = i1; best = v; i1 = e; }
      else if (v > best2) { best2 = v; i2 = e; }
    }
    float d = best - best2;
    float st = d / (d + 1e-6f);
    float et = expf(st);
    e_idx[0] = i1; gate_v[0] = et / (et + 1.0f);
    e_idx[1] = i2; gate_v[1] = 1.0f / (et + 1.0f);
  }

  // ---- early B-tile preload for expert 0 (overlaps x staging) -------------
  bf16x8 bq[3][3];
  {
    const __bf16* w1l = pw1 + (size_t)e_idx[0] * (24 * 192 * 32)
                            + (size_t)(wn * 48 + ln) * 32 + q8;
#pragma unroll
    for (int k0 = 0; k0 < 3; ++k0)
#pragma unroll
      for (int jj = 0; jj < 3; ++jj)
        bq[k0][jj] = *(const bf16x8*)(w1l + (size_t)k0 * 6144 + jj * 512);
  }

  // ---- stage x tile 64x768 f32->bf16 (coalesced, b128 LDS writes) ---------
  const float* xbase = x + ((size_t)b * N_ + token0) * C_;
  for (int it = 0; it < 6; ++it) {
    int chunk = it * 1024 + tid;               // 0..6143
    int row = chunk / 96;
    int col8 = chunk - row * 96;
    const float* p = xbase + (size_t)row * C_ + col8 * 8;
    float4 v0 = *(const float4*)p;
    float4 v1 = *(const float4*)(p + 4);
    bf16x8 tv;
    tv[0] = (__bf16)v0.x; tv[1] = (__bf16)v0.y; tv[2] = (__bf16)v0.z; tv[3] = (__bf16)v0.w;
    tv[4] = (__bf16)v1.x; tv[5] = (__bf16)v1.y; tv[6] = (__bf16)v1.z; tv[7] = (__bf16)v1.w;
    *(bf16x8*)&xs[row][col8 * 8] = tv;
  }
  __syncthreads();

  f32x4 c2[12] = {};   // persistent y accumulator (gate folded into h)

  for (int kx = 0; kx < 2; ++kx) {
    const int e = e_idx[kx];
    const float g = gate_v[kx];

    // ---- GEMM1: h = x @ W1^T. M=16 (wm), N-slice 48 (wn), K=768 (24 kb).
    // Depth-3 rotation: slot kb%3 consumed then refilled with kb+3.
    const __bf16* w1l = pw1 + (size_t)e * (24 * 192 * 32)
                            + (size_t)(wn * 48 + ln) * 32 + q8;
    if (kx == 1) {
#pragma unroll
      for (int k0 = 0; k0 < 3; ++k0)
#pragma unroll
        for (int jj = 0; jj < 3; ++jj)
          bq[k0][jj] = *(const bf16x8*)(w1l + (size_t)k0 * 6144 + jj * 512);
    }
    bf16x8 aq[3];
#pragma unroll
    for (int k0 = 0; k0 < 3; ++k0)
      aq[k0] = *(const bf16x8*)&xs[arow + ln][k0 * 32 + q8];
    f32x4 c1[3] = {};
#pragma unroll
    for (int kb = 0; kb < 24; ++kb) {
      const int p = kb % 3;
#pragma unroll
      for (int jj = 0; jj < 3; ++jj)
        c1[jj] = __builtin_amdgcn_mfma_f32_16x16x32_bf16(aq[p], bq[p][jj], c1[jj], 0, 0, 0);
      if (kb < 21) {
        const int kn = kb + 3;
        const __bf16* nx = w1l + (size_t)kn * 6144;
#pragma unroll
        for (int jj = 0; jj < 3; ++jj) bq[p][jj] = *(const bf16x8*)(nx + jj * 512);
        aq[p] = *(const bf16x8*)&xs[arow + ln][kn * 32 + q8];
      }
    }
    // bias + exact gelu + gate scale -> hs (bf16)
#pragma unroll
    for (int jj = 0; jj < 3; ++jj) {
      int col = wn * 48 + jj * 16 + ln;
      float b1 = fc1_b[e * H_ + col];
#pragma unroll
      for (int r = 0; r < 4; ++r) {
        int row = arow + q4 + r;
        float v = c1[jj][r] + b1;
        float gl = 0.5f * v * (1.0f + erff(v * 0.70710678118f));
        hs[row][col] = (__bf16)(g * gl);
      }
    }
    __syncthreads();

    // ---- GEMM2: y += h @ W2^T. M=16 (wm), N-slice 192 (wn), K=192.
    // 12 steps (6 kb x 2 half-tiles); B ping-pong by step parity, A
    // ping-pong by kb parity (prefetched on odd steps into unused buffer).
    const __bf16* w2l = pw2 + (size_t)e * (6 * 768 * 32)
                            + (size_t)(wn * 192 + ln) * 32 + q8;
    bf16x8 bh[2][6], av[2];
#pragma unroll
    for (int jj = 0; jj < 6; ++jj) bh[0][jj] = *(const bf16x8*)(w2l + jj * 512);
    av[0] = *(const bf16x8*)&hs[arow + ln][q8];
#pragma unroll
    for (int st = 0; st < 12; ++st) {
      const int kb = st >> 1;
      const int half = st & 1;
      const int p = st & 1;
      if (st < 11) {
        const int s2 = st + 1;
        const int kb2 = s2 >> 1, half2 = s2 & 1;
        const __bf16* src = w2l + (size_t)kb2 * 24576;
#pragma unroll
        for (int jj = 0; jj < 6; ++jj)
          bh[p ^ 1][jj] = *(const bf16x8*)(src + (half2 * 6 + jj) * 512);
        if (half2 == 0)   // new kb next step: its A frag into the free slot
          av[kb2 & 1] = *(const bf16x8*)&hs[arow + ln][kb2 * 32 + q8];
      }
#pragma unroll
      for (int jj = 0; jj < 6; ++jj) {
        const int cj = half * 6 + jj;
        c2[cj] = __builtin_amdgcn_mfma_f32_16x16x32_bf16(av[kb & 1], bh[p][jj], c2[cj], 0, 0, 0);
      }
    }
    __syncthreads();   // protect hs before next expert overwrites
  }

  // epilogue: out = x + y (+ gate-weighted fc2_b)
  const float* xr = x + ((size_t)b * N_ + token0) * C_;
  float* outr = out + ((size_t)b * N_ + token0) * C_;
#pragma unroll
  for (int jj = 0; jj < 12; ++jj) {
    int col = wn * 192 + jj * 16 + ln;
    float b2t = gate_v[0] * fc2_b[e_idx[0] * C_ + col] +
                gate_v[1] * fc2_b[e_idx[1] * C_ + col];
#pragma unroll
    for (int r = 0; r < 4; ++r) {
      int row = arow + q4 + r;
      size_t off = (size_t)row * C_ + col;
      outr[off] = xr[off] + c2[jj][r] + b2t;
    }
  }
}

// ---------------------------------------------------------------------------
extern "C" void kernel_launch(void* const* d_in, const int* in_sizes, int n_in,
                              void* d_out, int out_size, void* d_ws, size_t ws_size,
                              hipStream_t stream) {
  const float* x      = (const float*)d_in[0];
  const int*   task   = (const int*)d_in[1];
  const float* eps    = (const float*)d_in[2];
  const float* gate_w = (const float*)d_in[3];
  const float* fc1_w  = (const float*)d_in[4];
  const float* fc1_b  = (const float*)d_in[5];
  const float* fc2_w  = (const float*)d_in[6];
  const float* fc2_b  = (const float*)d_in[7];
  float* out = (float*)d_out;

  // workspace: pw1 | pw2 | gwT | psums  (~4.95 MB)
  const size_t nW = (size_t)E_ * H_ * C_;              // 1179648
  __bf16* pw1 = (__bf16*)d_ws;
  __bf16* pw2 = pw1 + nW;
  float* gwT   = (float*)((char*)d_ws + 2 * nW * sizeof(__bf16));
  float* psums = gwT + 4 * 16 * C_;                    // 1024*8 floats

  prep_kernel<<<(nW / 4 + 255) / 256, 256, 0, stream>>>(fc1_w, fc2_w, gate_w,
                                                        pw1, pw2, gwT);
  gate_kernel<<<B_ * 64, 256, 0, stream>>>(x, task, eps, gwT, psums);

  hipFuncSetAttribute(reinterpret_cast<const void*>(expert_kernel),
                      hipFuncAttributeMaxDynamicSharedMemorySize, SMEM_EXPERT);
  expert_kernel<<<B_ * 16, 1024, SMEM_EXPERT, stream>>>(
      x, pw1, pw2, fc1_b, fc2_b, psums, out);
}

// Round 5
// 205.297 us; speedup vs baseline: 1.1105x; 1.1105x over previous
//
#include <hip/hip_runtime.h>

#define B_ 16
#define N_ 1024
#define C_ 768
#define E_ 8
#define H_ 192

typedef __bf16 bf16x8 __attribute__((ext_vector_type(8)));
typedef float  f32x4  __attribute__((ext_vector_type(4)));

// ---------------------------------------------------------------------------
// Kernel 1: prep. (a) pack fc1_w/fc2_w to bf16 in MFMA-B-fragment order:
//   pw1[e][kb=c/32][n=h][c%32], pw2[e][kb=h/32][n=c][h%32]
// (b) transpose gate_w to gwT[d][j][c] (f32); rows 0..7 clean, 8..15 noise.
// ---------------------------------------------------------------------------
__global__ __launch_bounds__(256) void prep_kernel(
    const float* __restrict__ w1, const float* __restrict__ w2,
    const float* __restrict__ gw,
    __bf16* __restrict__ pw1, __bf16* __restrict__ pw2,
    float* __restrict__ gwT) {
  int idx = blockIdx.x * 256 + threadIdx.x;            // float4 index
  const int nW4 = (E_ * H_ * C_) / 4;                  // 294912
  if (idx >= nW4) return;
  int flat = idx * 4;
  int e = flat / (H_ * C_);
  int r = flat - e * (H_ * C_);

  // w1: [e][h][c] -> pw1
  {
    float4 a = *(const float4*)(w1 + (size_t)flat);
    int n = r / C_;           // h
    int c = r - n * C_;       // c, %4==0
    size_t o = ((size_t)(e * 24 + (c >> 5)) * 192 + n) * 32 + (c & 31);
    pw1[o + 0] = (__bf16)a.x; pw1[o + 1] = (__bf16)a.y;
    pw1[o + 2] = (__bf16)a.z; pw1[o + 3] = (__bf16)a.w;
  }
  // w2: [e][c][h] -> pw2
  {
    float4 a = *(const float4*)(w2 + (size_t)flat);
    int n = r / H_;           // c index 0..767
    int h = r - n * H_;       // 0..191, %4==0
    size_t o = ((size_t)(e * 6 + (h >> 5)) * 768 + n) * 32 + (h & 31);
    pw2[o + 0] = (__bf16)a.x; pw2[o + 1] = (__bf16)a.y;
    pw2[o + 2] = (__bf16)a.z; pw2[o + 3] = (__bf16)a.w;
  }
  // gwT: [d][c][16] -> [d][j][c]
  if (idx < (4 * 16 * C_) / 4) {
    int f = idx * 4;
    int d = f / (16 * C_);
    int rr = f - d * (16 * C_);
    int j = rr / C_;
    int c = rr - j * C_;      // %4==0
    const float* src = gw + (size_t)d * C_ * 16 + j;
    float4 v;
    v.x = src[(size_t)(c + 0) * 16]; v.y = src[(size_t)(c + 1) * 16];
    v.z = src[(size_t)(c + 2) * 16]; v.w = src[(size_t)(c + 3) * 16];
    *(float4*)(gwT + (size_t)f) = v;
  }
}

// ---------------------------------------------------------------------------
// Kernel 2: gating. Grid = B*64 blocks, 16 tokens each, 256 thr (broadcast
// mapping: 16 lanes share one gwT row -> 4 addrs/wave). Per-block partial
// expert sums -> psums[bid][8] (no atomics, no memset).
// ---------------------------------------------------------------------------
__global__ __launch_bounds__(256, 3) void gate_kernel(
    const float* __restrict__ x, const int* __restrict__ task_ids,
    const float* __restrict__ eps, const float* __restrict__ gwT,
    float* __restrict__ psums) {
  const int b = blockIdx.x >> 6;
  const int token0 = (blockIdx.x & 63) * 16;
  const int tid = threadIdx.x;

  __shared__ __align__(16) float xt[16][772];   // pad 4: 2-way (free) reads
  __shared__ float sc[16][16];
  __shared__ float red[16][8];

  // stage 16x768 f32, coalesced: 3072 float4 / 256 thr = 12 each
  const float* xbase = x + ((size_t)b * N_ + token0) * C_;
  for (int it = 0; it < 12; ++it) {
    int chunk = it * 256 + tid;                 // 0..3071
    int row = chunk / 192;
    int col4 = chunk - row * 192;
    float4 v = *(const float4*)(xbase + (size_t)row * C_ + col4 * 4);
    *(float4*)&xt[row][col4 * 4] = v;
  }
  __syncthreads();

  const int t = tid & 15;
  const int j = tid >> 4;                       // 16 lanes share one j
  const int task = task_ids[b];
  const float* wrow = gwT + ((size_t)task * 16 + j) * C_;
  float acc = 0.0f;
#pragma unroll 4
  for (int c = 0; c < C_; c += 4) {
    float4 xv = *(const float4*)&xt[t][c];
    float4 wv = *(const float4*)(wrow + c);
    acc += xv.x * wv.x + xv.y * wv.y + xv.z * wv.z + xv.w * wv.w;
  }
  sc[t][j] = acc;
  __syncthreads();
  if (j < 8) {
    float clean = sc[t][j];
    float raw = sc[t][j + 8];
    float sp = (raw > 20.0f) ? raw : log1pf(expf(raw));
    red[t][j] = clean +
        eps[((size_t)b * N_ + token0 + t) * E_ + j] * (sp + 0.01f);
  }
  __syncthreads();
  if (tid < 8) {
    float s = 0.0f;
#pragma unroll
    for (int tt = 0; tt < 16; ++tt) s += red[tt][tid];
    psums[(size_t)blockIdx.x * 8 + tid] = s;
  }
}

// ---------------------------------------------------------------------------
// Kernel 3: top-2 + 2-expert adapter. Grid = 512 blocks x 256 thr (4 waves,
// wave = wn N-slice, M=32 rows/wave -> 6 MFMAs per 3 B-loads, the proven
// per-wave shape), 32 tokens/block, LDS 62.5 KB -> 2 BLOCKS PER CU: one
// block's HBM phases (staging/epilogue) overlap the sibling's L2/VALU
// phases (GEMM/GELU), attacking the phase-serialization that capped R3.
// XCD-pinned: bid&7 = XCD, 2 samples/XCD -> expert set ~2.4 MB L2-resident.
// GEMM1 prefetch depth 4, GEMM2 B depth-3 / A 3-slot (R3 pipeline).
// MFMA 16x16x32 bf16; C/D: col=lane&15, row=(lane>>4)*4+reg.
// ---------------------------------------------------------------------------
#define SMEM_EXPERT (32 * 776 * 2 + 32 * 200 * 2 + 32)   // 62496 B

__global__ __launch_bounds__(256, 2) void expert_kernel(
    const float* __restrict__ x, const __bf16* __restrict__ pw1,
    const __bf16* __restrict__ pw2, const float* __restrict__ fc1_b,
    const float* __restrict__ fc2_b, const float* __restrict__ psums,
    float* __restrict__ out) {
  const int bid = blockIdx.x;
  const int sxc = bid >> 3;                    // 0..63 within an XCD
  const int b = (bid & 7) * 2 + (sxc >> 5);    // 2 consecutive samples / XCD
  const int token0 = (sxc & 31) * 32;
  const int tid = threadIdx.x;
  const int wave = tid >> 6;                   // wn N-slice (0..3)
  const int wn = wave;
  const int lane = tid & 63;
  const int ln = lane & 15;
  const int q8 = (lane >> 4) * 8;
  const int q4 = (lane >> 4) * 4;

  extern __shared__ char smem[];
  __bf16 (*xs)[776] = reinterpret_cast<__bf16(*)[776]>(smem);          // 49664
  __bf16 (*hs)[200] = reinterpret_cast<__bf16(*)[200]>(smem + 49664);  // 12800
  float* smc = reinterpret_cast<float*>(smem + 49664 + 12800);         // 32

  // ---- per-sample gate sums: wave w reduces e=w and e=w+4 -----------------
#pragma unroll
  for (int e2 = wave; e2 < 8; e2 += 4) {
    float v = psums[(((size_t)b << 6) | lane) * 8 + e2];
#pragma unroll
    for (int off = 32; off; off >>= 1) v += __shfl_down(v, off);
    if (lane == 0) smc[e2] = v;
  }
  __syncthreads();

  // top-2 (tie rule matches lax.top_k: strict >, stable)
  int e_idx[2]; float gate_v[2];
  {
    float best = -INFINITY, best2 = -INFINITY;
    int i1 = 0, i2 = 0;
#pragma unroll
    for (int e = 0; e < E_; ++e) {
      float v = smc[e];
      if (v > best) { best2 = best; i2 = i1; best = v; i1 = e; }
      else if (v > best2) { best2 = v; i2 = e; }
    }
    float d = best - best2;
    float st = d / (d + 1e-6f);
    float et = expf(st);
    e_idx[0] = i1; gate_v[0] = et / (et + 1.0f);
    e_idx[1] = i2; gate_v[1] = 1.0f / (et + 1.0f);
  }

  // ---- early B-tile preload for expert 0 (overlaps x staging) -------------
  bf16x8 bq[4][3];
  {
    const __bf16* w1l = pw1 + (size_t)e_idx[0] * (24 * 192 * 32)
                            + (size_t)(wn * 48 + ln) * 32 + q8;
#pragma unroll
    for (int k0 = 0; k0 < 4; ++k0)
#pragma unroll
      for (int jj = 0; jj < 3; ++jj)
        bq[k0][jj] = *(const bf16x8*)(w1l + (size_t)k0 * 6144 + jj * 512);
  }

  // ---- stage x tile 32x768 f32->bf16 (coalesced, b128 LDS writes) ---------
  const float* xbase = x + ((size_t)b * N_ + token0) * C_;
  for (int it = 0; it < 12; ++it) {
    int chunk = it * 256 + tid;                // 0..3071
    int row = chunk / 96;                      // 96 8-float chunks per row
    int col8 = chunk - row * 96;
    const float* p = xbase + (size_t)row * C_ + col8 * 8;
    float4 v0 = *(const float4*)p;
    float4 v1 = *(const float4*)(p + 4);
    bf16x8 tv;
    tv[0] = (__bf16)v0.x; tv[1] = (__bf16)v0.y; tv[2] = (__bf16)v0.z; tv[3] = (__bf16)v0.w;
    tv[4] = (__bf16)v1.x; tv[5] = (__bf16)v1.y; tv[6] = (__bf16)v1.z; tv[7] = (__bf16)v1.w;
    *(bf16x8*)&xs[row][col8 * 8] = tv;
  }
  __syncthreads();

  f32x4 c2[2][12] = {};   // persistent y accumulator (gate folded into h)

  for (int kx = 0; kx < 2; ++kx) {
    const int e = e_idx[kx];
    const float g = gate_v[kx];

    // ---- GEMM1: h = x @ W1^T. M=32 (2 frags), N-slice 48 (wn), K=768.
    // Depth-4: slots 0..3 preloaded; consume slot kb&3, refill with kb+4.
    const __bf16* w1l = pw1 + (size_t)e * (24 * 192 * 32)
                            + (size_t)(wn * 48 + ln) * 32 + q8;
    if (kx == 1) {
#pragma unroll
      for (int k0 = 0; k0 < 4; ++k0)
#pragma unroll
        for (int jj = 0; jj < 3; ++jj)
          bq[k0][jj] = *(const bf16x8*)(w1l + (size_t)k0 * 6144 + jj * 512);
    }
    bf16x8 aq[4][2];
#pragma unroll
    for (int k0 = 0; k0 < 4; ++k0) {
      aq[k0][0] = *(const bf16x8*)&xs[ln][k0 * 32 + q8];
      aq[k0][1] = *(const bf16x8*)&xs[16 + ln][k0 * 32 + q8];
    }
    f32x4 c1[2][3] = {};
#pragma unroll
    for (int kb = 0; kb < 24; ++kb) {
      const int p = kb & 3;
#pragma unroll
      for (int jj = 0; jj < 3; ++jj) {
        c1[0][jj] = __builtin_amdgcn_mfma_f32_16x16x32_bf16(aq[p][0], bq[p][jj], c1[0][jj], 0, 0, 0);
        c1[1][jj] = __builtin_amdgcn_mfma_f32_16x16x32_bf16(aq[p][1], bq[p][jj], c1[1][jj], 0, 0, 0);
      }
      if (kb < 20) {
        const int kn = kb + 4;
        const __bf16* nx = w1l + (size_t)kn * 6144;
#pragma unroll
        for (int jj = 0; jj < 3; ++jj) bq[p][jj] = *(const bf16x8*)(nx + jj * 512);
        aq[p][0] = *(const bf16x8*)&xs[ln][kn * 32 + q8];
        aq[p][1] = *(const bf16x8*)&xs[16 + ln][kn * 32 + q8];
      }
    }
    // bias + exact gelu + gate scale -> hs (bf16)
#pragma unroll
    for (int jj = 0; jj < 3; ++jj) {
      int col = wn * 48 + jj * 16 + ln;
      float b1 = fc1_b[e * H_ + col];
#pragma unroll
      for (int m = 0; m < 2; ++m) {
#pragma unroll
        for (int r = 0; r < 4; ++r) {
          int row = m * 16 + q4 + r;
          float v = c1[m][jj][r] + b1;
          float gl = 0.5f * v * (1.0f + erff(v * 0.70710678118f));
          hs[row][col] = (__bf16)(g * gl);
        }
      }
    }
    __syncthreads();

    // ---- GEMM2: y += h @ W2^T. M=32, N-slice 192 (wn), K=192.
    // 12 steps (6 kb x 2 half-tiles); B depth-3 ([3][6] rotation,
    // load-after-consume), A 3-slot rotation (av[kb%3]).
    const __bf16* w2l = pw2 + (size_t)e * (6 * 768 * 32)
                            + (size_t)(wn * 192 + ln) * 32 + q8;
    bf16x8 bh[3][6], av[3][2];
#pragma unroll
    for (int s0 = 0; s0 < 3; ++s0) {
      const __bf16* src = w2l + (size_t)(s0 >> 1) * 24576;
#pragma unroll
      for (int jj = 0; jj < 6; ++jj)
        bh[s0][jj] = *(const bf16x8*)(src + ((s0 & 1) * 6 + jj) * 512);
    }
    av[0][0] = *(const bf16x8*)&hs[ln][q8];
    av[0][1] = *(const bf16x8*)&hs[16 + ln][q8];
    av[1][0] = *(const bf16x8*)&hs[ln][32 + q8];
    av[1][1] = *(const bf16x8*)&hs[16 + ln][32 + q8];
#pragma unroll
    for (int st = 0; st < 12; ++st) {
      const int kb = st >> 1;
      const int half = st & 1;
      const int p = st % 3;
      const int as = kb % 3;
#pragma unroll
      for (int jj = 0; jj < 6; ++jj) {
        const int cj = half * 6 + jj;
        c2[0][cj] = __builtin_amdgcn_mfma_f32_16x16x32_bf16(av[as][0], bh[p][jj], c2[0][cj], 0, 0, 0);
        c2[1][cj] = __builtin_amdgcn_mfma_f32_16x16x32_bf16(av[as][1], bh[p][jj], c2[1][cj], 0, 0, 0);
      }
      if (st < 9) {
        const int s2 = st + 3;
        const int kb2 = s2 >> 1, half2 = s2 & 1;
        const __bf16* src = w2l + (size_t)kb2 * 24576;
#pragma unroll
        for (int jj = 0; jj < 6; ++jj)
          bh[p][jj] = *(const bf16x8*)(src + (half2 * 6 + jj) * 512);
        if (half2 == 0) {   // st odd: next-next kb's A frags, slot kb2%3 free
          av[kb2 % 3][0] = *(const bf16x8*)&hs[ln][kb2 * 32 + q8];
          av[kb2 % 3][1] = *(const bf16x8*)&hs[16 + ln][kb2 * 32 + q8];
        }
      }
    }
    __syncthreads();   // protect hs before next expert overwrites
  }

  // epilogue: out = x + y (+ gate-weighted fc2_b)
  const float* xr = x + ((size_t)b * N_ + token0) * C_;
  float* outr = out + ((size_t)b * N_ + token0) * C_;
#pragma unroll
  for (int jj = 0; jj < 12; ++jj) {
    int col = wn * 192 + jj * 16 + ln;
    float b2t = gate_v[0] * fc2_b[e_idx[0] * C_ + col] +
                gate_v[1] * fc2_b[e_idx[1] * C_ + col];
#pragma unroll
    for (int m = 0; m < 2; ++m) {
#pragma unroll
      for (int r = 0; r < 4; ++r) {
        int row = m * 16 + q4 + r;
        size_t off = (size_t)row * C_ + col;
        outr[off] = xr[off] + c2[m][jj][r] + b2t;
      }
    }
  }
}

// ---------------------------------------------------------------------------
extern "C" void kernel_launch(void* const* d_in, const int* in_sizes, int n_in,
                              void* d_out, int out_size, void* d_ws, size_t ws_size,
                              hipStream_t stream) {
  const float* x      = (const float*)d_in[0];
  const int*   task   = (const int*)d_in[1];
  const float* eps    = (const float*)d_in[2];
  const float* gate_w = (const float*)d_in[3];
  const float* fc1_w  = (const float*)d_in[4];
  const float* fc1_b  = (const float*)d_in[5];
  const float* fc2_w  = (const float*)d_in[6];
  const float* fc2_b  = (const float*)d_in[7];
  float* out = (float*)d_out;

  // workspace: pw1 | pw2 | gwT | psums  (~4.95 MB)
  const size_t nW = (size_t)E_ * H_ * C_;              // 1179648
  __bf16* pw1 = (__bf16*)d_ws;
  __bf16* pw2 = pw1 + nW;
  float* gwT   = (float*)((char*)d_ws + 2 * nW * sizeof(__bf16));
  float* psums = gwT + 4 * 16 * C_;                    // 1024*8 floats

  prep_kernel<<<(nW / 4 + 255) / 256, 256, 0, stream>>>(fc1_w, fc2_w, gate_w,
                                                        pw1, pw2, gwT);
  gate_kernel<<<B_ * 64, 256, 0, stream>>>(x, task, eps, gwT, psums);

  hipFuncSetAttribute(reinterpret_cast<const void*>(expert_kernel),
                      hipFuncAttributeMaxDynamicSharedMemorySize, SMEM_EXPERT);
  expert_kernel<<<B_ * 32, 256, SMEM_EXPERT, stream>>>(
      x, pw1, pw2, fc1_b, fc2_b, psums, out);
}